// Round 3
// baseline (233.036 us; speedup 1.0000x reference)
//
#include <hip/hip_runtime.h>
#include <math.h>

// Reverse cumulative max (suffix max) along last dim.
// x: (8,1,2048,2048) fp32 -> 16384 rows of W=2048. One wave per row-slice.
//
// Round 3 analysis: round 2 (perfectly coalesced, no LDS) ran at the SAME
// 81 us / 2.47 TB/s as round 1 -> not an addressing problem. VALUBusy 8%,
// avg wave lifetime ~24 us for 8 KiB of work: the one-shot shape
// (burst 8 loads -> vmcnt(0) -> serial shuffle scan -> store -> die) leaves
// the memory pipe unfed most of each wave's life. fillBuffer proves 6.7 TB/s
// on these buffers.
//
// Fix: persistent waves, 4 rows per wave, register double-buffering:
// issue row i+1's loads, then scan+store row i. Scan latency and store issue
// overlap the next row's HBM reads. Nontemporal stores keep the 128 MiB
// output stream from evicting the L3-resident input.
// (Round 4: nontemporal builtin needs a native ext_vector_type, not the
// HIP_vector_type wrapper -- bit-cast at the store site.)

#define ROW_W 2048
#define LANES 64
#define CHUNKS 8               // float4 per lane per row (8*64*4 = 2048)
#define WAVES_PER_BLOCK 4
#define ROWS_PER_WAVE 4

typedef float nativef4 __attribute__((ext_vector_type(4)));

__global__ __launch_bounds__(256) void suffix_max_kernel(
    const float* __restrict__ x, float* __restrict__ out, int nrows) {
  const int lane = threadIdx.x & 63;
  const int wid  = (blockIdx.x << 2) | (threadIdx.x >> 6);  // global wave id
  const int nw   = gridDim.x << 2;                          // total waves

  // Issue one row's loads (coalesced: instr k reads float4s [64k,64k+64)).
  auto loadrow = [&](float4 (&v)[CHUNKS], int row) {
    if (row < nrows) {
      const float4* __restrict__ p = (const float4*)(x + (size_t)row * ROW_W) + lane;
#pragma unroll
      for (int k = 0; k < CHUNKS; ++k) v[k] = p[k * LANES];
    }
  };

  // Suffix-max scan of one row held lane-strided in v[], then nt-store it.
  auto process = [&](float4 (&v)[CHUNKS], int row) {
    if (row >= nrows) return;
    // 1) suffix max inside each float4.
    float inc[CHUNKS];
#pragma unroll
    for (int k = 0; k < CHUNKS; ++k) {
      v[k].z = fmaxf(v[k].z, v[k].w);
      v[k].y = fmaxf(v[k].y, v[k].z);
      v[k].x = fmaxf(v[k].x, v[k].y);
      inc[k] = v[k].x;
    }
    // 2) eight independent 64-lane suffix scans (fmaxf idempotent -> no guards).
#pragma unroll
    for (int off = 1; off < LANES; off <<= 1) {
#pragma unroll
      for (int k = 0; k < CHUNKS; ++k) {
        float o = __shfl_down(inc[k], off, LANES);
        inc[k] = fmaxf(inc[k], o);
      }
    }
    float tot[CHUNKS], excl[CHUNKS];
#pragma unroll
    for (int k = 0; k < CHUNKS; ++k) tot[k] = __shfl(inc[k], 0, LANES);
#pragma unroll
    for (int k = 0; k < CHUNKS; ++k) {
      float e = __shfl_down(inc[k], 1, LANES);
      excl[k] = (lane == 63) ? -INFINITY : e;
    }
    // 3) serial fold across chunks, right to left.
    float tail = -INFINITY;
#pragma unroll
    for (int k = CHUNKS - 1; k >= 0; --k) {
      const float e = fmaxf(excl[k], tail);
      v[k].x = fmaxf(v[k].x, e);
      v[k].y = fmaxf(v[k].y, e);
      v[k].z = fmaxf(v[k].z, e);
      v[k].w = fmaxf(v[k].w, e);
      tail = fmaxf(tail, tot[k]);
    }
    // Coalesced nontemporal stores (don't pollute L2/L3; input stays resident).
    nativef4* __restrict__ q = (nativef4*)(out + (size_t)row * ROW_W) + lane;
#pragma unroll
    for (int k = 0; k < CHUNKS; ++k) {
      nativef4 nv;
      nv.x = v[k].x; nv.y = v[k].y; nv.z = v[k].z; nv.w = v[k].w;
      __builtin_nontemporal_store(nv, &q[k * LANES]);
    }
  };

  // Software pipeline over ROWS_PER_WAVE=4 strided rows, static a/b ping-pong.
  float4 a[CHUNKS], b[CHUNKS];
  const int r0 = wid;
  loadrow(a, r0);
  loadrow(b, r0 + nw);
  process(a, r0);
  loadrow(a, r0 + 2 * nw);
  process(b, r0 + nw);
  loadrow(b, r0 + 3 * nw);
  process(a, r0 + 2 * nw);
  process(b, r0 + 3 * nw);
}

extern "C" void kernel_launch(void* const* d_in, const int* in_sizes, int n_in,
                              void* d_out, int out_size, void* d_ws, size_t ws_size,
                              hipStream_t stream) {
  const float* x = (const float*)d_in[0];
  float* out = (float*)d_out;
  const int nrows = out_size / ROW_W;  // 16384
  // 4 waves/block * 4 rows/wave = 16 rows per block.
  const int blocks = (nrows + WAVES_PER_BLOCK * ROWS_PER_WAVE - 1) /
                     (WAVES_PER_BLOCK * ROWS_PER_WAVE);   // 1024
  suffix_max_kernel<<<blocks, 256, 0, stream>>>(x, out, nrows);
}

// Round 4
// 219.770 us; speedup vs baseline: 1.0604x; 1.0604x over previous
//
#include <hip/hip_runtime.h>
#include <math.h>

// Reverse cumulative max (suffix max) along last dim.
// x: (8,1,2048,2048) fp32 -> 16384 rows of W=2048. One wave per row.
//
// Round 4 analysis: three structurally different kernels (LDS transpose /
// coalesced one-shot / persistent pipelined) at 33/60/29% occupancy ALL hit
// exactly 2.47 TB/s HBM, 81 us. Fixed service-rate wall, not latency or
// scan cost. Distinguishing feature vs the 6.3 TB/s copy ubench: our
// working set (128 MiB in + 128 MiB out) == 256 MiB == Infinity Cache
// capacity -> FETCH_SIZE shows half the input L3-resident; output stores
// write-allocate and thrash the input out mid-iteration. Fix under test:
// nontemporal on BOTH loads and stores so both streams bypass LLC
// allocation and stream HBM-direct like the copy regime.
// Tell: FETCH_SIZE 64 MiB -> 128 MiB and time 81 -> ~45 us if right.

#define ROW_W 2048
#define LANES 64
#define CHUNKS 8               // float4 per lane (8*64*4 = 2048)
#define WAVES_PER_BLOCK 4

typedef float nf4 __attribute__((ext_vector_type(4)));

__global__ __launch_bounds__(256) void suffix_max_kernel(
    const float* __restrict__ x, float* __restrict__ out, int nrows) {
  const int lane = threadIdx.x & 63;
  const int row  = blockIdx.x * WAVES_PER_BLOCK + (threadIdx.x >> 6);
  if (row >= nrows) return;

  const nf4* __restrict__ p = (const nf4*)(x   + (size_t)row * ROW_W) + lane;
  nf4* __restrict__       q = (nf4*)      (out + (size_t)row * ROW_W) + lane;

  // Nontemporal coalesced loads: instr k reads float4s [64k,64k+64) -> 1 KiB.
  nf4 v[CHUNKS];
#pragma unroll
  for (int k = 0; k < CHUNKS; ++k)
    v[k] = __builtin_nontemporal_load(&p[k * LANES]);

  // 1) Suffix max inside each float4 (right-to-left).
  float inc[CHUNKS];
#pragma unroll
  for (int k = 0; k < CHUNKS; ++k) {
    v[k].z = fmaxf(v[k].z, v[k].w);
    v[k].y = fmaxf(v[k].y, v[k].z);
    v[k].x = fmaxf(v[k].x, v[k].y);
    inc[k] = v[k].x;
  }

  // 2) Eight independent 64-lane suffix scans (fmaxf idempotent -> no guards).
#pragma unroll
  for (int off = 1; off < LANES; off <<= 1) {
#pragma unroll
    for (int k = 0; k < CHUNKS; ++k) {
      float o = __shfl_down(inc[k], off, LANES);
      inc[k] = fmaxf(inc[k], o);
    }
  }

  float tot[CHUNKS], excl[CHUNKS];
#pragma unroll
  for (int k = 0; k < CHUNKS; ++k) tot[k] = __shfl(inc[k], 0, LANES);
#pragma unroll
  for (int k = 0; k < CHUNKS; ++k) {
    float e = __shfl_down(inc[k], 1, LANES);
    excl[k] = (lane == 63) ? -INFINITY : e;
  }

  // 3) Serial fold across chunks, right to left.
  float tail = -INFINITY;
#pragma unroll
  for (int k = CHUNKS - 1; k >= 0; --k) {
    const float e = fmaxf(excl[k], tail);
    v[k].x = fmaxf(v[k].x, e);
    v[k].y = fmaxf(v[k].y, e);
    v[k].z = fmaxf(v[k].z, e);
    v[k].w = fmaxf(v[k].w, e);
    tail = fmaxf(tail, tot[k]);
  }

  // Nontemporal coalesced stores: 1 KiB per instruction.
#pragma unroll
  for (int k = 0; k < CHUNKS; ++k)
    __builtin_nontemporal_store(v[k], &q[k * LANES]);
}

extern "C" void kernel_launch(void* const* d_in, const int* in_sizes, int n_in,
                              void* d_out, int out_size, void* d_ws, size_t ws_size,
                              hipStream_t stream) {
  const float* x = (const float*)d_in[0];
  float* out = (float*)d_out;
  const int nrows = out_size / ROW_W;  // 16384
  const int blocks = (nrows + WAVES_PER_BLOCK - 1) / WAVES_PER_BLOCK;
  suffix_max_kernel<<<blocks, 256, 0, stream>>>(x, out, nrows);
}